// Round 6
// baseline (82.454 us; speedup 1.0000x reference)
//
#include <hip/hip_runtime.h>
#include <hip/hip_bf16.h>

#define BN 4096
#define DD 128
#define NCLS 64
#define MARGIN_F 1.0f
#define NPAN 64         // i-panels of 64 rows
#define NCHK 16         // j-chunks of 256 cols
#define NSB (NPAN*NCHK) // 1024 negsum blocks (+1 scatter block)

typedef __attribute__((ext_vector_type(8))) short bf16x8;
typedef __attribute__((ext_vector_type(4))) float f32x4;

__device__ __forceinline__ unsigned short f2bf(float f) {
    __hip_bfloat16 h = __float2bfloat16(f);
    return *reinterpret_cast<unsigned short*>(&h);
}

// K1: fp32->bf16, row norms, class histogram (fused).
__global__ __launch_bounds__(256) void prep_kernel(
    const float* __restrict__ score,
    const int* __restrict__ tgt,
    unsigned short* __restrict__ sbf,
    float* __restrict__ mag,
    int* __restrict__ bins)
{
    const int tid = threadIdx.x;
    const int w = tid >> 6, lane = tid & 63;
    const int row = blockIdx.x * 8 + w * 2 + (lane >> 5);
    const int l32 = lane & 31;
    float4 v = *reinterpret_cast<const float4*>(score + (size_t)row * DD + l32 * 4);
    ushort4 u;
    u.x = f2bf(v.x); u.y = f2bf(v.y); u.z = f2bf(v.z); u.w = f2bf(v.w);
    *reinterpret_cast<ushort4*>(sbf + (size_t)row * DD + l32 * 4) = u;
    float s = v.x * v.x + v.y * v.y + v.z * v.z + v.w * v.w;
    #pragma unroll
    for (int o = 16; o > 0; o >>= 1) s += __shfl_xor(s, o);
    if (l32 == 0) {
        mag[row] = s;
        atomicAdd(&bins[tgt[row]], 1);
    }
}

// K2: neg partial sums, NO atomics. Wave owns 16 i-rows (A-frags in regs),
// streams a 256-col j-chunk; per-lane partial row sums; one f32x4 store/wave.
// Block NSB is a special block doing the class-sort scatter concurrently.
__global__ __launch_bounds__(256) void negsum_kernel(
    const unsigned short* __restrict__ sbf,
    const float* __restrict__ mag,
    const int* __restrict__ tgt,
    float* __restrict__ negp,
    const int* __restrict__ bins,
    int* __restrict__ cursor,
    int* __restrict__ perm)
{
    const int bid = blockIdx.x;
    const int tid = threadIdx.x;
    const int wid = tid >> 6;
    const int lane = tid & 63;

    if (bid == NSB) {
        // class-sorted permutation: per-wave redundant scan, then scatter
        int v = (lane < NCLS) ? bins[lane] : 0;
        int inc = v;
        #pragma unroll
        for (int o = 1; o < 64; o <<= 1) {
            int uu = __shfl_up(inc, o);
            if (lane >= o) inc += uu;
        }
        const int exc = inc - v;
        for (int i = tid; i < BN; i += 256) {
            const int c = tgt[i];
            const int pos = __shfl(exc, c) + atomicAdd(&cursor[c], 1);
            perm[pos] = i;
        }
        return;
    }

    const int panel = bid & (NPAN - 1);
    const int jc = bid >> 6;
    const int lhi = lane >> 4, llo = lane & 15;
    const int i0 = panel * 64 + wid * 16;

    // A fragments for this wave's 16 rows, K=128 (held in registers)
    bf16x8 a[4];
    #pragma unroll
    for (int kk = 0; kk < 4; ++kk)
        a[kk] = *reinterpret_cast<const bf16x8*>(sbf + (size_t)(i0 + llo) * DD + kk * 32 + lhi * 8);

    const int ibase = i0 + lhi * 4;
    f32x4 magi = *reinterpret_cast<const f32x4*>(mag + ibase);
    int4 ti4 = *reinterpret_cast<const int4*>(tgt + ibase);
    const int t0 = ti4.x, t1 = ti4.y, t2 = ti4.z, t3 = ti4.w;

    f32x4 rsum = {0.0f, 0.0f, 0.0f, 0.0f};

    #pragma unroll 2
    for (int jt = 0; jt < 16; ++jt) {
        const int jrow = jc * 256 + jt * 16 + llo;
        const unsigned short* bp = sbf + (size_t)jrow * DD + lhi * 8;
        bf16x8 b0 = *reinterpret_cast<const bf16x8*>(bp);
        bf16x8 b1 = *reinterpret_cast<const bf16x8*>(bp + 32);
        bf16x8 b2 = *reinterpret_cast<const bf16x8*>(bp + 64);
        bf16x8 b3 = *reinterpret_cast<const bf16x8*>(bp + 96);
        const float magj = mag[jrow];
        const int tjv = tgt[jrow];

        f32x4 acc = {0.0f, 0.0f, 0.0f, 0.0f};
        acc = __builtin_amdgcn_mfma_f32_16x16x32_bf16(a[0], b0, acc, 0, 0, 0);
        acc = __builtin_amdgcn_mfma_f32_16x16x32_bf16(a[1], b1, acc, 0, 0, 0);
        acc = __builtin_amdgcn_mfma_f32_16x16x32_bf16(a[2], b2, acc, 0, 0, 0);
        acc = __builtin_amdgcn_mfma_f32_16x16x32_bf16(a[3], b3, acc, 0, 0, 0);

        // C/D layout: col = lane&15 (j=jrow), row = lhi*4 + r (i=ibase+r)
        #pragma unroll
        for (int r = 0; r < 4; ++r) {
            const int ti = (r == 0) ? t0 : (r == 1) ? t1 : (r == 2) ? t2 : t3;
            float d2 = magi[r] + magj - 2.0f * acc[r];
            d2 = fmaxf(d2, 0.0f);
            float dist = sqrtf(d2);
            rsum[r] += (ti != tjv) ? __expf(MARGIN_F - dist) : 0.0f;
        }
    }

    // reduce over the 16 llo lanes (xor 1,2,4,8 stays within the lhi group)
    #pragma unroll
    for (int r = 0; r < 4; ++r) {
        #pragma unroll
        for (int o = 1; o < 16; o <<= 1)
            rsum[r] += __shfl_xor(rsum[r], o);
    }
    if (llo == 0)
        *reinterpret_cast<f32x4*>(negp + (size_t)jc * BN + ibase) = rsum;
}

// K3: fold 16 chunk-partials into neg[i].
__global__ __launch_bounds__(256) void reduce_neg_kernel(
    const float* __restrict__ negp, float* __restrict__ neg)
{
    const int i = blockIdx.x * 256 + threadIdx.x;
    float s = 0.0f;
    #pragma unroll
    for (int jc = 0; jc < NCHK; ++jc) s += negp[(size_t)jc * BN + i];
    neg[i] = s;
}

// K4: per-class loss (gathered MFMA tile) + tail-block finalize.
__global__ __launch_bounds__(256) void loss_kernel(
    const unsigned short* __restrict__ sbf,
    const float* __restrict__ mag,
    const float* __restrict__ neg,
    const int* __restrict__ bins,
    const int* __restrict__ perm,
    float2* __restrict__ part,
    int* __restrict__ tail,
    float* __restrict__ out)
{
    const int c = blockIdx.x;
    const int tid = threadIdx.x;
    const int wid = tid >> 6, lane = tid & 63;

    __shared__ int sbase, scnt;
    if (tid < 64) {
        int v = (lane < c) ? bins[lane] : 0;
        #pragma unroll
        for (int o = 32; o > 0; o >>= 1) v += __shfl_xor(v, o);
        if (lane == 0) { sbase = v; scnt = bins[c]; }
    }
    __syncthreads();
    const int base = sbase, n_c = scnt;

    const int wr = wid >> 1, wc = wid & 1;
    const int p0 = wr * 64, q0 = wc * 64;
    const int lhi = lane >> 4, llo = lane & 15;

    float lsum = 0.0f, lcnt = 0.0f;
    const bool active = (n_c > 0) && (wc >= wr) && (p0 < n_c) && (q0 < n_c);
    if (active) {
        int opA[4], opB[4];
        #pragma unroll
        for (int m = 0; m < 4; ++m) {
            const int p = p0 + m * 16 + llo;
            opA[m] = perm[base + min(p, n_c - 1)];
        }
        #pragma unroll
        for (int n = 0; n < 4; ++n) {
            const int q = q0 + n * 16 + llo;
            opB[n] = perm[base + min(q, n_c - 1)];
        }
        f32x4 acc[4][4] = {};
        #pragma unroll
        for (int kk = 0; kk < 4; ++kk) {
            const int koff = kk * 32 + lhi * 8;
            bf16x8 a[4], b[4];
            #pragma unroll
            for (int m = 0; m < 4; ++m)
                a[m] = *reinterpret_cast<const bf16x8*>(sbf + (size_t)opA[m] * DD + koff);
            #pragma unroll
            for (int n = 0; n < 4; ++n)
                b[n] = *reinterpret_cast<const bf16x8*>(sbf + (size_t)opB[n] * DD + koff);
            #pragma unroll
            for (int m = 0; m < 4; ++m)
                #pragma unroll
                for (int n = 0; n < 4; ++n)
                    acc[m][n] = __builtin_amdgcn_mfma_f32_16x16x32_bf16(a[m], b[n], acc[m][n], 0, 0, 0);
        }

        float magjv[4], nsj[4]; int qv[4];
        #pragma unroll
        for (int n = 0; n < 4; ++n) {
            qv[n] = q0 + n * 16 + llo;
            magjv[n] = mag[opB[n]];
            nsj[n] = neg[opB[n]];
        }

        #pragma unroll
        for (int m = 0; m < 4; ++m) {
            #pragma unroll
            for (int r = 0; r < 4; ++r) {
                const int p = p0 + m * 16 + lhi * 4 + r;
                const bool pv = (p < n_c);
                const int io = perm[base + min(p, n_c - 1)];
                const float magiv = mag[io];
                const float nsi = neg[io];
                #pragma unroll
                for (int n = 0; n < 4; ++n) {
                    if (pv && qv[n] > p && qv[n] < n_c) {
                        float d2 = magiv + magjv[n] - 2.0f * acc[m][n][r];
                        d2 = fmaxf(d2, 0.0f);
                        float dist = sqrtf(d2);
                        float ln = __logf(nsi + nsj[n]);
                        float uu = fmaxf(ln + dist, 0.0f);
                        lsum += uu * uu;
                        lcnt += 1.0f;
                    }
                }
            }
        }
    }

    #pragma unroll
    for (int o = 32; o > 0; o >>= 1) {
        lsum += __shfl_xor(lsum, o);
        lcnt += __shfl_xor(lcnt, o);
    }
    __shared__ float2 wpart[4];
    __shared__ int dlast;
    if (lane == 0) wpart[wid] = make_float2(lsum, lcnt);
    __syncthreads();
    if (tid == 0) {
        float s = 0.0f, cc = 0.0f;
        #pragma unroll
        for (int w = 0; w < 4; ++w) { s += wpart[w].x; cc += wpart[w].y; }
        part[c] = make_float2(s, cc);
        __threadfence();
        dlast = (atomicAdd(tail, 1) == NCLS - 1) ? 1 : 0;
    }
    __syncthreads();
    if (dlast && tid < 64) {
        __threadfence();
        float2 p = part[lane];
        float s = p.x, cc = p.y;
        #pragma unroll
        for (int o = 32; o > 0; o >>= 1) {
            s += __shfl_xor(s, o);
            cc += __shfl_xor(cc, o);
        }
        if (lane == 0) out[0] = s / (2.0f * fmaxf(cc, 1.0f));
    }
}

extern "C" void kernel_launch(void* const* d_in, const int* in_sizes, int n_in,
                              void* d_out, int out_size, void* d_ws, size_t ws_size,
                              hipStream_t stream) {
    const float* score = (const float*)d_in[0];
    const int* tgt = (const int*)d_in[1];
    float* out = (float*)d_out;

    char* ws = (char*)d_ws;
    unsigned short* sbf = (unsigned short*)ws;               // 1 MB
    float* mag = (float*)(ws + (size_t)BN * DD * 2);         // 16 KB
    float* neg = mag + BN;                                   // 16 KB
    float* negp = neg + BN;                                  // 16*4096*4 = 256 KB
    int* perm = (int*)(negp + (size_t)NCHK * BN);            // 16 KB
    int* bins = perm + BN;                                   // 64 ints
    int* cursor = bins + NCLS;                               // 64 ints
    int* tail = cursor + NCLS;                               // 1 int (+1 pad)
    float2* part = (float2*)(tail + 2);                      // 64 float2

    // zero bins + cursor + tail
    hipMemsetAsync(bins, 0, (2 * NCLS + 2) * sizeof(int), stream);

    prep_kernel<<<512, 256, 0, stream>>>(score, tgt, sbf, mag, bins);
    negsum_kernel<<<NSB + 1, 256, 0, stream>>>(sbf, mag, tgt, negp, bins, cursor, perm);
    reduce_neg_kernel<<<BN / 256, 256, 0, stream>>>(negp, neg);
    loss_kernel<<<NCLS, 256, 0, stream>>>(sbf, mag, neg, bins, perm, part, tail, out);
}

// Round 7
// 58.771 us; speedup vs baseline: 1.4030x; 1.4030x over previous
//
#include <hip/hip_runtime.h>
#include <hip/hip_bf16.h>

#define BN 4096
#define DD 128
#define NCLS 64
#define MARGIN_F 1.0f
#define NPAN 64         // i-panels of 64 rows
#define NCHK 16         // j-chunks of 256 cols
#define NSB (NPAN*NCHK) // 1024 negsum blocks (+1 sort block)

typedef __attribute__((ext_vector_type(8))) short bf16x8;
typedef __attribute__((ext_vector_type(4))) float f32x4;

__device__ __forceinline__ unsigned short f2bf(float f) {
    __hip_bfloat16 h = __float2bfloat16(f);
    return *reinterpret_cast<unsigned short*>(&h);
}

// K1: fp32->bf16 convert + row squared norms. No global state needed zeroed.
__global__ __launch_bounds__(256) void prep_kernel(
    const float* __restrict__ score,
    unsigned short* __restrict__ sbf,
    float* __restrict__ mag)
{
    const int tid = threadIdx.x;
    const int w = tid >> 6, lane = tid & 63;
    const int row = blockIdx.x * 8 + w * 2 + (lane >> 5);
    const int l32 = lane & 31;
    float4 v = *reinterpret_cast<const float4*>(score + (size_t)row * DD + l32 * 4);
    ushort4 u;
    u.x = f2bf(v.x); u.y = f2bf(v.y); u.z = f2bf(v.z); u.w = f2bf(v.w);
    *reinterpret_cast<ushort4*>(sbf + (size_t)row * DD + l32 * 4) = u;
    float s = v.x * v.x + v.y * v.y + v.z * v.z + v.w * v.w;
    #pragma unroll
    for (int o = 16; o > 0; o >>= 1) s += __shfl_xor(s, o);
    if (l32 == 0) mag[row] = s;
}

// K2: neg partial sums (atomic-free, register accumulate).
// Block NSB: self-contained class sort (LDS hist + scan + scatter).
__global__ __launch_bounds__(256) void negsum_kernel(
    const unsigned short* __restrict__ sbf,
    const float* __restrict__ mag,
    const int* __restrict__ tgt,
    float* __restrict__ negp,
    int* __restrict__ perm,
    int* __restrict__ cls_off,
    int* __restrict__ cls_cnt)
{
    const int bid = blockIdx.x;
    const int tid = threadIdx.x;
    const int wid = tid >> 6;
    const int lane = tid & 63;

    if (bid == NSB) {
        // LDS-local histogram -> scan -> scatter; no pre-zeroed globals.
        __shared__ int h[NCLS], cur[NCLS];
        if (tid < NCLS) h[tid] = 0;
        __syncthreads();
        for (int i = tid; i < BN; i += 256) atomicAdd(&h[tgt[i]], 1);
        __syncthreads();
        if (tid < NCLS) {
            const int v = h[tid];
            int inc = v;
            #pragma unroll
            for (int o = 1; o < 64; o <<= 1) {
                int uu = __shfl_up(inc, o);
                if (tid >= o) inc += uu;
            }
            const int exc = inc - v;
            cls_off[tid] = exc;
            cls_cnt[tid] = v;
            cur[tid] = exc;
        }
        __syncthreads();
        for (int i = tid; i < BN; i += 256) {
            const int pos = atomicAdd(&cur[tgt[i]], 1);
            perm[pos] = i;
        }
        return;
    }

    const int panel = bid & (NPAN - 1);
    const int jc = bid >> 6;
    const int lhi = lane >> 4, llo = lane & 15;
    const int i0 = panel * 64 + wid * 16;

    // A fragments for this wave's 16 rows, K=128 (registers)
    bf16x8 a[4];
    #pragma unroll
    for (int kk = 0; kk < 4; ++kk)
        a[kk] = *reinterpret_cast<const bf16x8*>(sbf + (size_t)(i0 + llo) * DD + kk * 32 + lhi * 8);

    const int ibase = i0 + lhi * 4;
    f32x4 magi = *reinterpret_cast<const f32x4*>(mag + ibase);
    int4 ti4 = *reinterpret_cast<const int4*>(tgt + ibase);
    const int t0 = ti4.x, t1 = ti4.y, t2 = ti4.z, t3 = ti4.w;

    // preload the chunk's 256 mag/tgt values: 4 per lane, fetched per-jt via shfl
    float magv[4]; int tgv[4];
    #pragma unroll
    for (int s = 0; s < 4; ++s) {
        magv[s] = mag[jc * 256 + s * 64 + lane];
        tgv[s] = tgt[jc * 256 + s * 64 + lane];
    }

    f32x4 rsum = {0.0f, 0.0f, 0.0f, 0.0f};

    #pragma unroll 2
    for (int jt = 0; jt < 16; ++jt) {
        const int jrow = jc * 256 + jt * 16 + llo;
        const unsigned short* bp = sbf + (size_t)jrow * DD + lhi * 8;
        bf16x8 b0 = *reinterpret_cast<const bf16x8*>(bp);
        bf16x8 b1 = *reinterpret_cast<const bf16x8*>(bp + 32);
        bf16x8 b2 = *reinterpret_cast<const bf16x8*>(bp + 64);
        bf16x8 b3 = *reinterpret_cast<const bf16x8*>(bp + 96);
        const int srcl = (jt & 3) * 16 + llo;
        const float magj = __shfl(magv[jt >> 2], srcl);
        const int tjv = __shfl(tgv[jt >> 2], srcl);

        f32x4 acc = {0.0f, 0.0f, 0.0f, 0.0f};
        acc = __builtin_amdgcn_mfma_f32_16x16x32_bf16(a[0], b0, acc, 0, 0, 0);
        acc = __builtin_amdgcn_mfma_f32_16x16x32_bf16(a[1], b1, acc, 0, 0, 0);
        acc = __builtin_amdgcn_mfma_f32_16x16x32_bf16(a[2], b2, acc, 0, 0, 0);
        acc = __builtin_amdgcn_mfma_f32_16x16x32_bf16(a[3], b3, acc, 0, 0, 0);

        // C/D layout: col = lane&15 (j=jrow), row = lhi*4 + r (i=ibase+r)
        #pragma unroll
        for (int r = 0; r < 4; ++r) {
            const int ti = (r == 0) ? t0 : (r == 1) ? t1 : (r == 2) ? t2 : t3;
            float d2 = magi[r] + magj - 2.0f * acc[r];
            d2 = fmaxf(d2, 0.0f);
            float dist = sqrtf(d2);
            rsum[r] += (ti != tjv) ? __expf(MARGIN_F - dist) : 0.0f;
        }
    }

    // reduce over the 16 llo lanes (xor 1,2,4,8 stays within the lhi group)
    #pragma unroll
    for (int r = 0; r < 4; ++r) {
        #pragma unroll
        for (int o = 1; o < 16; o <<= 1)
            rsum[r] += __shfl_xor(rsum[r], o);
    }
    if (llo == 0)
        *reinterpret_cast<f32x4*>(negp + (size_t)jc * BN + ibase) = rsum;
}

// K3: fold 16 chunk-partials into neg[i].
__global__ __launch_bounds__(256) void reduce_neg_kernel(
    const float* __restrict__ negp, float* __restrict__ neg)
{
    const int i = blockIdx.x * 256 + threadIdx.x;
    float s = 0.0f;
    #pragma unroll
    for (int jc = 0; jc < NCHK; ++jc) s += negp[(size_t)jc * BN + i];
    neg[i] = s;
}

// K4: per-class loss over same-class pairs (gathered MFMA tile).
__global__ __launch_bounds__(256) void loss_kernel(
    const unsigned short* __restrict__ sbf,
    const float* __restrict__ mag,
    const float* __restrict__ neg,
    const int* __restrict__ perm,
    const int* __restrict__ cls_off,
    const int* __restrict__ cls_cnt,
    float2* __restrict__ part)
{
    const int c = blockIdx.x;
    const int tid = threadIdx.x;
    const int wid = tid >> 6, lane = tid & 63;
    const int base = cls_off[c], n_c = cls_cnt[c];

    const int wr = wid >> 1, wc = wid & 1;
    const int p0 = wr * 64, q0 = wc * 64;
    const int lhi = lane >> 4, llo = lane & 15;

    float lsum = 0.0f, lcnt = 0.0f;
    const bool active = (n_c > 0) && (wc >= wr) && (p0 < n_c) && (q0 < n_c);
    if (active) {
        int opA[4], opB[4];
        #pragma unroll
        for (int m = 0; m < 4; ++m) {
            const int p = p0 + m * 16 + llo;
            opA[m] = perm[base + min(p, n_c - 1)];
        }
        #pragma unroll
        for (int n = 0; n < 4; ++n) {
            const int q = q0 + n * 16 + llo;
            opB[n] = perm[base + min(q, n_c - 1)];
        }
        f32x4 acc[4][4] = {};
        #pragma unroll
        for (int kk = 0; kk < 4; ++kk) {
            const int koff = kk * 32 + lhi * 8;
            bf16x8 a[4], b[4];
            #pragma unroll
            for (int m = 0; m < 4; ++m)
                a[m] = *reinterpret_cast<const bf16x8*>(sbf + (size_t)opA[m] * DD + koff);
            #pragma unroll
            for (int n = 0; n < 4; ++n)
                b[n] = *reinterpret_cast<const bf16x8*>(sbf + (size_t)opB[n] * DD + koff);
            #pragma unroll
            for (int m = 0; m < 4; ++m)
                #pragma unroll
                for (int n = 0; n < 4; ++n)
                    acc[m][n] = __builtin_amdgcn_mfma_f32_16x16x32_bf16(a[m], b[n], acc[m][n], 0, 0, 0);
        }

        float magjv[4], nsj[4]; int qv[4];
        #pragma unroll
        for (int n = 0; n < 4; ++n) {
            qv[n] = q0 + n * 16 + llo;
            magjv[n] = mag[opB[n]];
            nsj[n] = neg[opB[n]];
        }

        #pragma unroll
        for (int m = 0; m < 4; ++m) {
            #pragma unroll
            for (int r = 0; r < 4; ++r) {
                const int p = p0 + m * 16 + lhi * 4 + r;
                const bool pv = (p < n_c);
                const int io = perm[base + min(p, n_c - 1)];
                const float magiv = mag[io];
                const float nsi = neg[io];
                #pragma unroll
                for (int n = 0; n < 4; ++n) {
                    if (pv && qv[n] > p && qv[n] < n_c) {
                        float d2 = magiv + magjv[n] - 2.0f * acc[m][n][r];
                        d2 = fmaxf(d2, 0.0f);
                        float dist = sqrtf(d2);
                        float ln = __logf(nsi + nsj[n]);
                        float uu = fmaxf(ln + dist, 0.0f);
                        lsum += uu * uu;
                        lcnt += 1.0f;
                    }
                }
            }
        }
    }

    #pragma unroll
    for (int o = 32; o > 0; o >>= 1) {
        lsum += __shfl_xor(lsum, o);
        lcnt += __shfl_xor(lcnt, o);
    }
    __shared__ float2 wpart[4];
    if (lane == 0) wpart[wid] = make_float2(lsum, lcnt);
    __syncthreads();
    if (tid == 0) {
        float s = 0.0f, cc = 0.0f;
        #pragma unroll
        for (int w = 0; w < 4; ++w) { s += wpart[w].x; cc += wpart[w].y; }
        part[c] = make_float2(s, cc);
    }
}

// K5: reduce 64 class partials -> scalar.
__global__ __launch_bounds__(64) void finalize_kernel(
    const float2* __restrict__ part, float* __restrict__ out)
{
    const int t = threadIdx.x;
    float2 p = part[t];
    float s = p.x, c = p.y;
    #pragma unroll
    for (int o = 32; o > 0; o >>= 1) {
        s += __shfl_xor(s, o);
        c += __shfl_xor(c, o);
    }
    if (t == 0) out[0] = s / (2.0f * fmaxf(c, 1.0f));
}

extern "C" void kernel_launch(void* const* d_in, const int* in_sizes, int n_in,
                              void* d_out, int out_size, void* d_ws, size_t ws_size,
                              hipStream_t stream) {
    const float* score = (const float*)d_in[0];
    const int* tgt = (const int*)d_in[1];
    float* out = (float*)d_out;

    char* ws = (char*)d_ws;
    unsigned short* sbf = (unsigned short*)ws;               // 1 MB
    float* mag = (float*)(ws + (size_t)BN * DD * 2);         // 16 KB
    float* neg = mag + BN;                                   // 16 KB
    float* negp = neg + BN;                                  // 256 KB
    int* perm = (int*)(negp + (size_t)NCHK * BN);            // 16 KB
    int* cls_off = perm + BN;                                // 256 B
    int* cls_cnt = cls_off + NCLS;                           // 256 B
    float2* part = (float2*)(cls_cnt + NCLS);                // 512 B

    prep_kernel<<<512, 256, 0, stream>>>(score, sbf, mag);
    negsum_kernel<<<NSB + 1, 256, 0, stream>>>(sbf, mag, tgt, negp, perm, cls_off, cls_cnt);
    reduce_neg_kernel<<<BN / 256, 256, 0, stream>>>(negp, neg);
    loss_kernel<<<NCLS, 256, 0, stream>>>(sbf, mag, neg, perm, cls_off, cls_cnt, part);
    finalize_kernel<<<1, 64, 0, stream>>>(part, out);
}

// Round 8
// 57.782 us; speedup vs baseline: 1.4270x; 1.0171x over previous
//
#include <hip/hip_runtime.h>
#include <hip/hip_bf16.h>

#define BN 4096
#define DD 128
#define SD 136          // padded row stride (elems): 272B, breaks pow2 striding
#define NCLS 64
#define MARGIN_F 1.0f
#define NSQ 1024        // 32x32 grid of 128x128 tiles
#define NSLOT 64        // negp partial slots per row (32 bj x 2 wc)

typedef __attribute__((ext_vector_type(8))) short bf16x8;
typedef __attribute__((ext_vector_type(4))) float f32x4;

__device__ __forceinline__ unsigned short f2bf(float f) {
    __hip_bfloat16 h = __float2bfloat16(f);
    return *reinterpret_cast<unsigned short*>(&h);
}

// K1: fp32->bf16 convert (padded stride) + row squared norms.
__global__ __launch_bounds__(256) void prep_kernel(
    const float* __restrict__ score,
    unsigned short* __restrict__ sbf,
    float* __restrict__ mag)
{
    const int tid = threadIdx.x;
    const int w = tid >> 6, lane = tid & 63;
    const int row = blockIdx.x * 8 + w * 2 + (lane >> 5);
    const int l32 = lane & 31;
    float4 v = *reinterpret_cast<const float4*>(score + (size_t)row * DD + l32 * 4);
    ushort4 u;
    u.x = f2bf(v.x); u.y = f2bf(v.y); u.z = f2bf(v.z); u.w = f2bf(v.w);
    *reinterpret_cast<ushort4*>(sbf + (size_t)row * SD + l32 * 4) = u;
    float s = v.x * v.x + v.y * v.y + v.z * v.z + v.w * v.w;
    #pragma unroll
    for (int o = 16; o > 0; o >>= 1) s += __shfl_xor(s, o);
    if (l32 == 0) mag[row] = s;
}

// K2: neg partial sums. R2 fat-wave structure: 128x128 tile/block, 4 waves 2x2,
// 64x64 per wave, 4x4 frags (16 indep acc chains), batched loads per kk.
// Atomic-free: per-wave row sums -> negp[slot][row], slot = bj*2+wc.
// Block NSQ: self-contained class sort (LDS hist + scan + scatter).
__global__ __launch_bounds__(256, 2) void negsum_kernel(
    const unsigned short* __restrict__ sbf,
    const float* __restrict__ mag,
    const int* __restrict__ tgt,
    float* __restrict__ negp,
    int* __restrict__ perm,
    int* __restrict__ cls_off,
    int* __restrict__ cls_cnt)
{
    const int bid = blockIdx.x;
    const int tid = threadIdx.x;
    const int wid = tid >> 6;
    const int lane = tid & 63;

    if (bid == NSQ) {
        __shared__ int h[NCLS], cur[NCLS];
        if (tid < NCLS) h[tid] = 0;
        __syncthreads();
        for (int i = tid; i < BN; i += 256) atomicAdd(&h[tgt[i]], 1);
        __syncthreads();
        if (tid < NCLS) {
            const int v = h[tid];
            int inc = v;
            #pragma unroll
            for (int o = 1; o < 64; o <<= 1) {
                int uu = __shfl_up(inc, o);
                if (tid >= o) inc += uu;
            }
            const int exc = inc - v;
            cls_off[tid] = exc;
            cls_cnt[tid] = v;
            cur[tid] = exc;
        }
        __syncthreads();
        for (int i = tid; i < BN; i += 256) {
            const int pos = atomicAdd(&cur[tgt[i]], 1);
            perm[pos] = i;
        }
        return;
    }

    const int bi = bid & 31, bj = bid >> 5;
    const int wr = wid >> 1, wc = wid & 1;
    const int i0 = bi * 128 + wr * 64;
    const int j0 = bj * 128 + wc * 64;
    const int lhi = lane >> 4, llo = lane & 15;

    f32x4 acc[4][4] = {};
    #pragma unroll
    for (int kk = 0; kk < 4; ++kk) {
        const int koff = kk * 32 + lhi * 8;
        bf16x8 a[4], b[4];
        #pragma unroll
        for (int m = 0; m < 4; ++m)
            a[m] = *reinterpret_cast<const bf16x8*>(sbf + (size_t)(i0 + m * 16 + llo) * SD + koff);
        #pragma unroll
        for (int n = 0; n < 4; ++n)
            b[n] = *reinterpret_cast<const bf16x8*>(sbf + (size_t)(j0 + n * 16 + llo) * SD + koff);
        #pragma unroll
        for (int m = 0; m < 4; ++m)
            #pragma unroll
            for (int n = 0; n < 4; ++n)
                acc[m][n] = __builtin_amdgcn_mfma_f32_16x16x32_bf16(a[m], b[n], acc[m][n], 0, 0, 0);
    }

    float magj[4]; int tj[4];
    #pragma unroll
    for (int n = 0; n < 4; ++n) {
        const int j = j0 + n * 16 + llo;
        magj[n] = mag[j];
        tj[n] = tgt[j];
    }

    const int slot = bj * 2 + wc;
    // C/D layout: col = lane&15 (j), row = (lane>>4)*4 + r (i)
    #pragma unroll
    for (int m = 0; m < 4; ++m) {
        const int ibase = i0 + m * 16 + lhi * 4;
        f32x4 magi = *reinterpret_cast<const f32x4*>(mag + ibase);
        int4 ti4 = *reinterpret_cast<const int4*>(tgt + ibase);
        const int* tip = &ti4.x;
        f32x4 rs = {0.0f, 0.0f, 0.0f, 0.0f};
        #pragma unroll
        for (int r = 0; r < 4; ++r) {
            const int ti = tip[r];
            float s = 0.0f;
            #pragma unroll
            for (int n = 0; n < 4; ++n) {
                float d2 = fmaxf(magi[r] + magj[n] - 2.0f * acc[m][n][r], 0.0f);
                float dist = __builtin_amdgcn_sqrtf(d2);
                s += (ti != tj[n]) ? __expf(MARGIN_F - dist) : 0.0f;
            }
            #pragma unroll
            for (int o = 1; o < 16; o <<= 1) s += __shfl_xor(s, o);
            rs[r] = s;
        }
        if (llo == 0)
            *reinterpret_cast<f32x4*>(negp + (size_t)slot * BN + ibase) = rs;
    }
}

// K3: fold 64 slot-partials into neg[i].
__global__ __launch_bounds__(256) void reduce_neg_kernel(
    const float* __restrict__ negp, float* __restrict__ neg)
{
    const int i = blockIdx.x * 256 + threadIdx.x;
    float s = 0.0f;
    #pragma unroll
    for (int k = 0; k < NSLOT; ++k) s += negp[(size_t)k * BN + i];
    neg[i] = s;
}

// K4: per-class loss over same-class pairs (gathered MFMA tile).
__global__ __launch_bounds__(256) void loss_kernel(
    const unsigned short* __restrict__ sbf,
    const float* __restrict__ mag,
    const float* __restrict__ neg,
    const int* __restrict__ perm,
    const int* __restrict__ cls_off,
    const int* __restrict__ cls_cnt,
    float2* __restrict__ part)
{
    const int c = blockIdx.x;
    const int tid = threadIdx.x;
    const int wid = tid >> 6, lane = tid & 63;
    const int base = cls_off[c], n_c = cls_cnt[c];

    const int wr = wid >> 1, wc = wid & 1;
    const int p0 = wr * 64, q0 = wc * 64;
    const int lhi = lane >> 4, llo = lane & 15;

    float lsum = 0.0f, lcnt = 0.0f;
    const bool active = (n_c > 0) && (wc >= wr) && (p0 < n_c) && (q0 < n_c);
    if (active) {
        int opA[4], opB[4];
        #pragma unroll
        for (int m = 0; m < 4; ++m) {
            const int p = p0 + m * 16 + llo;
            opA[m] = perm[base + min(p, n_c - 1)];
        }
        #pragma unroll
        for (int n = 0; n < 4; ++n) {
            const int q = q0 + n * 16 + llo;
            opB[n] = perm[base + min(q, n_c - 1)];
        }
        f32x4 acc[4][4] = {};
        #pragma unroll
        for (int kk = 0; kk < 4; ++kk) {
            const int koff = kk * 32 + lhi * 8;
            bf16x8 a[4], b[4];
            #pragma unroll
            for (int m = 0; m < 4; ++m)
                a[m] = *reinterpret_cast<const bf16x8*>(sbf + (size_t)opA[m] * SD + koff);
            #pragma unroll
            for (int n = 0; n < 4; ++n)
                b[n] = *reinterpret_cast<const bf16x8*>(sbf + (size_t)opB[n] * SD + koff);
            #pragma unroll
            for (int m = 0; m < 4; ++m)
                #pragma unroll
                for (int n = 0; n < 4; ++n)
                    acc[m][n] = __builtin_amdgcn_mfma_f32_16x16x32_bf16(a[m], b[n], acc[m][n], 0, 0, 0);
        }

        float magjv[4], nsj[4]; int qv[4];
        #pragma unroll
        for (int n = 0; n < 4; ++n) {
            qv[n] = q0 + n * 16 + llo;
            magjv[n] = mag[opB[n]];
            nsj[n] = neg[opB[n]];
        }

        #pragma unroll
        for (int m = 0; m < 4; ++m) {
            #pragma unroll
            for (int r = 0; r < 4; ++r) {
                const int p = p0 + m * 16 + lhi * 4 + r;
                const bool pv = (p < n_c);
                const int io = perm[base + min(p, n_c - 1)];
                const float magiv = mag[io];
                const float nsi = neg[io];
                #pragma unroll
                for (int n = 0; n < 4; ++n) {
                    if (pv && qv[n] > p && qv[n] < n_c) {
                        float d2 = fmaxf(magiv + magjv[n] - 2.0f * acc[m][n][r], 0.0f);
                        float dist = __builtin_amdgcn_sqrtf(d2);
                        float ln = __logf(nsi + nsj[n]);
                        float uu = fmaxf(ln + dist, 0.0f);
                        lsum += uu * uu;
                        lcnt += 1.0f;
                    }
                }
            }
        }
    }

    #pragma unroll
    for (int o = 32; o > 0; o >>= 1) {
        lsum += __shfl_xor(lsum, o);
        lcnt += __shfl_xor(lcnt, o);
    }
    __shared__ float2 wpart[4];
    if (lane == 0) wpart[wid] = make_float2(lsum, lcnt);
    __syncthreads();
    if (tid == 0) {
        float s = 0.0f, cc = 0.0f;
        #pragma unroll
        for (int w = 0; w < 4; ++w) { s += wpart[w].x; cc += wpart[w].y; }
        part[c] = make_float2(s, cc);
    }
}

// K5: reduce 64 class partials -> scalar.
__global__ __launch_bounds__(64) void finalize_kernel(
    const float2* __restrict__ part, float* __restrict__ out)
{
    const int t = threadIdx.x;
    float2 p = part[t];
    float s = p.x, c = p.y;
    #pragma unroll
    for (int o = 32; o > 0; o >>= 1) {
        s += __shfl_xor(s, o);
        c += __shfl_xor(c, o);
    }
    if (t == 0) out[0] = s / (2.0f * fmaxf(c, 1.0f));
}

extern "C" void kernel_launch(void* const* d_in, const int* in_sizes, int n_in,
                              void* d_out, int out_size, void* d_ws, size_t ws_size,
                              hipStream_t stream) {
    const float* score = (const float*)d_in[0];
    const int* tgt = (const int*)d_in[1];
    float* out = (float*)d_out;

    char* ws = (char*)d_ws;
    unsigned short* sbf = (unsigned short*)ws;               // 4096*136*2 ≈ 1.09 MB
    float* mag = (float*)(ws + (size_t)BN * SD * 2 + 64);    // 16 KB (64B-aligned pad)
    float* neg = mag + BN;                                   // 16 KB
    float* negp = neg + BN;                                  // 64*4096*4 = 1 MB
    int* perm = (int*)(negp + (size_t)NSLOT * BN);           // 16 KB
    int* cls_off = perm + BN;                                // 256 B
    int* cls_cnt = cls_off + NCLS;                           // 256 B
    float2* part = (float2*)(cls_cnt + NCLS);                // 512 B

    prep_kernel<<<512, 256, 0, stream>>>(score, sbf, mag);
    negsum_kernel<<<NSQ + 1, 256, 0, stream>>>(sbf, mag, tgt, negp, perm, cls_off, cls_cnt);
    reduce_neg_kernel<<<BN / 256, 256, 0, stream>>>(negp, neg);
    loss_kernel<<<NCLS, 256, 0, stream>>>(sbf, mag, neg, perm, cls_off, cls_cnt, part);
    finalize_kernel<<<1, 64, 0, stream>>>(part, out);
}

// Round 9
// 55.844 us; speedup vs baseline: 1.4765x; 1.0347x over previous
//
#include <hip/hip_runtime.h>
#include <hip/hip_bf16.h>

#define BN 4096
#define DD 128
#define SD 136          // padded row stride (elems): 272B
#define NCLS 64
#define MARGIN_F 1.0f
#define NSQ 1024        // 32x32 grid of 128x128 tiles
#define NSLOT 64        // negp partial slots per row (32 bj x 2 wc)

typedef __attribute__((ext_vector_type(8))) short bf16x8;
typedef __attribute__((ext_vector_type(4))) float f32x4;

__device__ __forceinline__ unsigned short f2bf(float f) {
    __hip_bfloat16 h = __float2bfloat16(f);
    return *reinterpret_cast<unsigned short*>(&h);
}

// K1: fp32->bf16 convert (padded stride) + row squared norms.
__global__ __launch_bounds__(256) void prep_kernel(
    const float* __restrict__ score,
    unsigned short* __restrict__ sbf,
    float* __restrict__ mag)
{
    const int tid = threadIdx.x;
    const int w = tid >> 6, lane = tid & 63;
    const int row = blockIdx.x * 8 + w * 2 + (lane >> 5);
    const int l32 = lane & 31;
    float4 v = *reinterpret_cast<const float4*>(score + (size_t)row * DD + l32 * 4);
    ushort4 u;
    u.x = f2bf(v.x); u.y = f2bf(v.y); u.z = f2bf(v.z); u.w = f2bf(v.w);
    *reinterpret_cast<ushort4*>(sbf + (size_t)row * SD + l32 * 4) = u;
    float s = v.x * v.x + v.y * v.y + v.z * v.z + v.w * v.w;
    #pragma unroll
    for (int o = 16; o > 0; o >>= 1) s += __shfl_xor(s, o);
    if (l32 == 0) mag[row] = s;
}

// K2: neg partial sums — PURE tile grid (no embedded sort block).
// 128x128 tile/block, 4 waves 2x2, 64x64/wave, 4x4 frags.
// Atomic-free: per-wave row sums -> negp[slot][row], slot = bj*2+wc.
__global__ __launch_bounds__(256, 2) void negsum_kernel(
    const unsigned short* __restrict__ sbf,
    const float* __restrict__ mag,
    const int* __restrict__ tgt,
    float* __restrict__ negp)
{
    const int bid = blockIdx.x;
    const int tid = threadIdx.x;
    const int wid = tid >> 6;
    const int lane = tid & 63;

    const int bi = bid & 31, bj = bid >> 5;
    const int wr = wid >> 1, wc = wid & 1;
    const int i0 = bi * 128 + wr * 64;
    const int j0 = bj * 128 + wc * 64;
    const int lhi = lane >> 4, llo = lane & 15;

    f32x4 acc[4][4] = {};
    #pragma unroll
    for (int kk = 0; kk < 4; ++kk) {
        const int koff = kk * 32 + lhi * 8;
        bf16x8 a[4], b[4];
        #pragma unroll
        for (int m = 0; m < 4; ++m)
            a[m] = *reinterpret_cast<const bf16x8*>(sbf + (size_t)(i0 + m * 16 + llo) * SD + koff);
        #pragma unroll
        for (int n = 0; n < 4; ++n)
            b[n] = *reinterpret_cast<const bf16x8*>(sbf + (size_t)(j0 + n * 16 + llo) * SD + koff);
        #pragma unroll
        for (int m = 0; m < 4; ++m)
            #pragma unroll
            for (int n = 0; n < 4; ++n)
                acc[m][n] = __builtin_amdgcn_mfma_f32_16x16x32_bf16(a[m], b[n], acc[m][n], 0, 0, 0);
    }

    float magj[4]; int tj[4];
    #pragma unroll
    for (int n = 0; n < 4; ++n) {
        const int j = j0 + n * 16 + llo;
        magj[n] = mag[j];
        tj[n] = tgt[j];
    }

    const int slot = bj * 2 + wc;
    // C/D layout: col = lane&15 (j), row = (lane>>4)*4 + r (i)
    #pragma unroll
    for (int m = 0; m < 4; ++m) {
        const int ibase = i0 + m * 16 + lhi * 4;
        f32x4 magi = *reinterpret_cast<const f32x4*>(mag + ibase);
        int4 ti4 = *reinterpret_cast<const int4*>(tgt + ibase);
        const int* tip = &ti4.x;
        f32x4 rs = {0.0f, 0.0f, 0.0f, 0.0f};
        #pragma unroll
        for (int r = 0; r < 4; ++r) {
            const int ti = tip[r];
            float s = 0.0f;
            #pragma unroll
            for (int n = 0; n < 4; ++n) {
                float d2 = fmaxf(magi[r] + magj[n] - 2.0f * acc[m][n][r], 0.0f);
                float dist = __builtin_amdgcn_sqrtf(d2);
                s += (ti != tj[n]) ? __expf(MARGIN_F - dist) : 0.0f;
            }
            #pragma unroll
            for (int o = 1; o < 16; o <<= 1) s += __shfl_xor(s, o);
            rs[r] = s;
        }
        if (llo == 0)
            *reinterpret_cast<f32x4*>(negp + (size_t)slot * BN + ibase) = rs;
    }
}

// K3: fold 64 slot-partials into neg[i].
__global__ __launch_bounds__(256) void reduce_neg_kernel(
    const float* __restrict__ negp, float* __restrict__ neg)
{
    const int i = blockIdx.x * 256 + threadIdx.x;
    float s = 0.0f;
    #pragma unroll
    for (int k = 0; k < NSLOT; ++k) s += negp[(size_t)k * BN + i];
    neg[i] = s;
}

// K4: per-class loss. Each block SELF-COMPACTS its class's row list
// (stable block-scan compaction into LDS) — no sort/perm machinery.
__global__ __launch_bounds__(256) void loss_kernel(
    const unsigned short* __restrict__ sbf,
    const float* __restrict__ mag,
    const float* __restrict__ neg,
    const int* __restrict__ tgt,
    float2* __restrict__ part)
{
    const int c = blockIdx.x;
    const int tid = threadIdx.x;
    const int wid = tid >> 6, lane = tid & 63;

    // ---- stable compaction: rows with tgt==c, ascending, into slist ----
    __shared__ int slist[256];
    __shared__ int wsum[4];
    __shared__ int snc;
    int4 tv[4];
    #pragma unroll
    for (int k = 0; k < 4; ++k)
        tv[k] = *reinterpret_cast<const int4*>(tgt + tid * 16 + k * 4);
    int cnt = 0;
    #pragma unroll
    for (int k = 0; k < 4; ++k) {
        const int* q = &tv[k].x;
        #pragma unroll
        for (int e = 0; e < 4; ++e) cnt += (q[e] == c) ? 1 : 0;
    }
    int inc = cnt;
    #pragma unroll
    for (int o = 1; o < 64; o <<= 1) {
        int u = __shfl_up(inc, o);
        if (lane >= o) inc += u;
    }
    if (lane == 63) wsum[wid] = inc;
    __syncthreads();
    int wpre = 0;
    #pragma unroll
    for (int w = 0; w < 4; ++w) wpre += (w < wid) ? wsum[w] : 0;
    if (tid == 255) snc = wpre + inc;
    int pos = wpre + inc - cnt;
    #pragma unroll
    for (int k = 0; k < 4; ++k) {
        const int* q = &tv[k].x;
        #pragma unroll
        for (int e = 0; e < 4; ++e) {
            if (q[e] == c && pos < 256) { slist[pos] = tid * 16 + k * 4 + e; ++pos; }
        }
    }
    __syncthreads();
    const int n_c = snc;

    const int wr = wid >> 1, wc = wid & 1;
    const int p0 = wr * 64, q0 = wc * 64;
    const int lhi = lane >> 4, llo = lane & 15;

    float lsum = 0.0f, lcnt = 0.0f;
    const bool active = (n_c > 0) && (wc >= wr) && (p0 < n_c) && (q0 < n_c);
    if (active) {
        int opA[4], opB[4];
        #pragma unroll
        for (int m = 0; m < 4; ++m) {
            const int p = p0 + m * 16 + llo;
            opA[m] = slist[min(p, n_c - 1)];
        }
        #pragma unroll
        for (int n = 0; n < 4; ++n) {
            const int q = q0 + n * 16 + llo;
            opB[n] = slist[min(q, n_c - 1)];
        }
        f32x4 acc[4][4] = {};
        #pragma unroll
        for (int kk = 0; kk < 4; ++kk) {
            const int koff = kk * 32 + lhi * 8;
            bf16x8 a[4], b[4];
            #pragma unroll
            for (int m = 0; m < 4; ++m)
                a[m] = *reinterpret_cast<const bf16x8*>(sbf + (size_t)opA[m] * SD + koff);
            #pragma unroll
            for (int n = 0; n < 4; ++n)
                b[n] = *reinterpret_cast<const bf16x8*>(sbf + (size_t)opB[n] * SD + koff);
            #pragma unroll
            for (int m = 0; m < 4; ++m)
                #pragma unroll
                for (int n = 0; n < 4; ++n)
                    acc[m][n] = __builtin_amdgcn_mfma_f32_16x16x32_bf16(a[m], b[n], acc[m][n], 0, 0, 0);
        }

        float magjv[4], nsj[4]; int qv[4];
        #pragma unroll
        for (int n = 0; n < 4; ++n) {
            qv[n] = q0 + n * 16 + llo;
            magjv[n] = mag[opB[n]];
            nsj[n] = neg[opB[n]];
        }

        #pragma unroll
        for (int m = 0; m < 4; ++m) {
            #pragma unroll
            for (int r = 0; r < 4; ++r) {
                const int p = p0 + m * 16 + lhi * 4 + r;
                const bool pv = (p < n_c);
                const int io = slist[min(p, n_c - 1)];
                const float magiv = mag[io];
                const float nsi = neg[io];
                #pragma unroll
                for (int n = 0; n < 4; ++n) {
                    if (pv && qv[n] > p && qv[n] < n_c) {
                        float d2 = fmaxf(magiv + magjv[n] - 2.0f * acc[m][n][r], 0.0f);
                        float dist = __builtin_amdgcn_sqrtf(d2);
                        float ln = __logf(nsi + nsj[n]);
                        float uu = fmaxf(ln + dist, 0.0f);
                        lsum += uu * uu;
                        lcnt += 1.0f;
                    }
                }
            }
        }
    }

    #pragma unroll
    for (int o = 32; o > 0; o >>= 1) {
        lsum += __shfl_xor(lsum, o);
        lcnt += __shfl_xor(lcnt, o);
    }
    __shared__ float2 wpart[4];
    if (lane == 0) wpart[wid] = make_float2(lsum, lcnt);
    __syncthreads();
    if (tid == 0) {
        float s = 0.0f, cc = 0.0f;
        #pragma unroll
        for (int w = 0; w < 4; ++w) { s += wpart[w].x; cc += wpart[w].y; }
        part[c] = make_float2(s, cc);
    }
}

// K5: reduce 64 class partials -> scalar.
__global__ __launch_bounds__(64) void finalize_kernel(
    const float2* __restrict__ part, float* __restrict__ out)
{
    const int t = threadIdx.x;
    float2 p = part[t];
    float s = p.x, c = p.y;
    #pragma unroll
    for (int o = 32; o > 0; o >>= 1) {
        s += __shfl_xor(s, o);
        c += __shfl_xor(c, o);
    }
    if (t == 0) out[0] = s / (2.0f * fmaxf(c, 1.0f));
}

extern "C" void kernel_launch(void* const* d_in, const int* in_sizes, int n_in,
                              void* d_out, int out_size, void* d_ws, size_t ws_size,
                              hipStream_t stream) {
    const float* score = (const float*)d_in[0];
    const int* tgt = (const int*)d_in[1];
    float* out = (float*)d_out;

    char* ws = (char*)d_ws;
    unsigned short* sbf = (unsigned short*)ws;               // 4096*136*2 ≈ 1.09 MB
    float* mag = (float*)(ws + (size_t)BN * SD * 2 + 64);    // 16 KB
    float* neg = mag + BN;                                   // 16 KB
    float* negp = neg + BN;                                  // 64*4096*4 = 1 MB
    float2* part = (float2*)(negp + (size_t)NSLOT * BN);     // 512 B

    prep_kernel<<<512, 256, 0, stream>>>(score, sbf, mag);
    negsum_kernel<<<NSQ, 256, 0, stream>>>(sbf, mag, tgt, negp);
    reduce_neg_kernel<<<BN / 256, 256, 0, stream>>>(negp, neg);
    loss_kernel<<<NCLS, 256, 0, stream>>>(sbf, mag, neg, tgt, part);
    finalize_kernel<<<1, 64, 0, stream>>>(part, out);
}